// Round 19
// baseline (116.749 us; speedup 1.0000x reference)
//
#include <hip/hip_runtime.h>
#include <hip/hip_bf16.h>
#include <stdint.h>

#define DMODEL 1024
#define NH 16
#define DKH 64
#define BB 2
#define SS 2048
#define MTOT (BB*SS)   // 4096

#define TP 136   // padded LDS stride (elems) for 128-wide tiles

using f32x4  = __attribute__((ext_vector_type(4))) float;
using bf16x8 = __attribute__((ext_vector_type(8))) __bf16;

// async global->LDS, 16B per lane. LDS dest must be wave-uniform base + lane*16.
#define GLL(g, l) __builtin_amdgcn_global_load_lds( \
    (const __attribute__((address_space(1))) unsigned int*)(g), \
    (__attribute__((address_space(3))) unsigned int*)(l), 16, 0, 0)

__device__ __forceinline__ unsigned short f2bf(float f) {
  union { float f; uint32_t u; } v; v.f = f;
  uint32_t r = v.u + 0x7FFFu + ((v.u >> 16) & 1u);
  return (unsigned short)(r >> 16);
}

// one launch converts X and all 4 weight matrices to bf16
__global__ __launch_bounds__(256) void cvt_all(
    const float* __restrict__ X,
    const float* __restrict__ w0, const float* __restrict__ w1,
    const float* __restrict__ w2, const float* __restrict__ w3,
    unsigned short* __restrict__ Xb,
    unsigned short* __restrict__ Wb)   // [Wq;Wk;Wv;Wo] contiguous
{
  const int bid = blockIdx.x;
  const float* src;
  unsigned short* dst;
  int i;
  if (bid < 2048) {                      // X: 4M elems = 2048 blocks
    src = X; dst = Xb; i = bid * 256 + threadIdx.x;
  } else {                               // each W: 1M elems = 512 blocks
    int t = bid - 2048;
    int z = t >> 9;
    src = (z == 0) ? w0 : (z == 1) ? w1 : (z == 2) ? w2 : w3;
    dst = Wb + (size_t)z * DMODEL * DMODEL;
    i = (t & 511) * 256 + threadIdx.x;
  }
  const float4* s4 = (const float4*)src;
  float4 a = s4[2*i], b = s4[2*i+1];
  uint4 o;
  o.x = (uint32_t)f2bf(a.x) | ((uint32_t)f2bf(a.y) << 16);
  o.y = (uint32_t)f2bf(a.z) | ((uint32_t)f2bf(a.w) << 16);
  o.z = (uint32_t)f2bf(b.x) | ((uint32_t)f2bf(b.y) << 16);
  o.w = (uint32_t)f2bf(b.z) | ((uint32_t)f2bf(b.w) << 16);
  *(uint4*)(dst + (size_t)i * 8) = o;
}

// ---- pipelined double-buffered NT-GEMM mainloop ----------------------------
// KU = k-unroll: BKT = 32*KU elems staged per step. KU=2 halves the step
// count (and per-step barrier/drain fixed cost) at identical math order.
template<int MI, int NI, int KU>
__device__ __forceinline__ void gemm_pipe(
    const unsigned short* __restrict__ A,
    const unsigned short* __restrict__ Bw,
    int m0, int n0, int K,
    unsigned short* As, unsigned short* Bs,
    f32x4 (&acc)[MI][NI])
{
  const int BKT = 32 * KU;
  const int BMl = MI * 32;
  const int BNl = NI * 32;
  const int tid = threadIdx.x;
  const int lane = tid & 63;
  const int w = tid >> 6;
  const int wr = w >> 1, wc = w & 1;
  const int lrow = lane & 15;
  const int g = lane >> 4;

  const f32x4 fzero = {0.f, 0.f, 0.f, 0.f};
  #pragma unroll
  for (int i = 0; i < MI; ++i)
    #pragma unroll
    for (int j = 0; j < NI; ++j)
      acc[i][j] = fzero;

  const int nk = K / BKT;

  // hoisted per-thread staging sources and LDS chunk offsets
  const unsigned short* aSrc[(MI * KU) / 2];
  const unsigned short* bSrc[(NI * KU) / 2];
  int aLds[(MI * KU) / 2], bLds[(NI * KU) / 2];
  #pragma unroll
  for (int c = 0; c < (MI * KU) / 2; ++c) {
    int i = tid + c * 256;
    int row, sc;
    if constexpr (KU == 1) { row = i >> 2; sc = (i & 3) ^ ((row >> 1) & 3); }
    else                   { row = i >> 3; sc = (i & 7) ^ (row & 7); }
    aSrc[c] = A + (size_t)(m0 + row) * K + sc * 8;
    aLds[c] = i * 8;
  }
  #pragma unroll
  for (int c = 0; c < (NI * KU) / 2; ++c) {
    int i = tid + c * 256;
    int row, sc;
    if constexpr (KU == 1) { row = i >> 2; sc = (i & 3) ^ ((row >> 1) & 3); }
    else                   { row = i >> 3; sc = (i & 7) ^ (row & 7); }
    bSrc[c] = Bw + (size_t)(n0 + row) * K + sc * 8;
    bLds[c] = i * 8;
  }
  // hoisted fragment read offsets (per k-sub-step u)
  int aOff[KU][MI], bOff[KU][NI];
  #pragma unroll
  for (int u = 0; u < KU; ++u) {
    #pragma unroll
    for (int mi = 0; mi < MI; ++mi) {
      int row = wr * (MI * 16) + mi * 16 + lrow;
      int ch = (KU == 1) ? (g ^ ((row >> 1) & 3)) : ((g + 4 * u) ^ (row & 7));
      aOff[u][mi] = row * BKT + ch * 8;
    }
    #pragma unroll
    for (int ni = 0; ni < NI; ++ni) {
      int row = wc * (NI * 16) + ni * 16 + lrow;
      int ch = (KU == 1) ? (g ^ ((row >> 1) & 3)) : ((g + 4 * u) ^ (row & 7));
      bOff[u][ni] = row * BKT + ch * 8;
    }
  }

  auto STAGE = [&](int k0, int buf) {
    #pragma unroll
    for (int c = 0; c < (MI * KU) / 2; ++c)
      GLL(aSrc[c] + k0, As + buf * (BMl * BKT) + aLds[c]);
    #pragma unroll
    for (int c = 0; c < (NI * KU) / 2; ++c)
      GLL(bSrc[c] + k0, Bs + buf * (BNl * BKT) + bLds[c]);
  };

  STAGE(0, 0);
  __syncthreads();
  for (int t = 0; t < nk; ++t) {
    const int cur = t & 1;
    if (t + 1 < nk) STAGE((t + 1) * BKT, cur ^ 1);

    const unsigned short* Ab = As + cur * (BMl * BKT);
    const unsigned short* Bb = Bs + cur * (BNl * BKT);
    #pragma unroll
    for (int u = 0; u < KU; ++u) {
      bf16x8 af[MI], bfr[NI];
      #pragma unroll
      for (int mi = 0; mi < MI; ++mi)
        af[mi] = *(const bf16x8*)(Ab + aOff[u][mi]);
      #pragma unroll
      for (int ni = 0; ni < NI; ++ni)
        bfr[ni] = *(const bf16x8*)(Bb + bOff[u][ni]);
      #pragma unroll
      for (int mi = 0; mi < MI; ++mi)
        #pragma unroll
        for (int ni = 0; ni < NI; ++ni)
          acc[mi][ni] = __builtin_amdgcn_mfma_f32_16x16x32_bf16(af[mi], bfr[ni], acc[mi][ni], 0, 0, 0);
    }

    __syncthreads();
  }
}

// ---- fused QKV projection + RoPE + head-split store (R18 proven) -----------
__global__ __launch_bounds__(256) void gemm_qkv(
    const unsigned short* __restrict__ Xb,
    const unsigned short* __restrict__ Wf,   // [3072][1024]
    const int* __restrict__ tpos,
    unsigned short* __restrict__ Qh,    // [B,H,S,64]
    unsigned short* __restrict__ Kh,    // [B,H,S,64]
    unsigned short* __restrict__ Vt)    // [B,H,64,S]
{
  __shared__ __align__(16) unsigned char smraw[65536];  // 2buf x (A+B) x 128x64
  unsigned short* sm = (unsigned short*)smraw;
  unsigned short* As = sm;                 // 2*128*64 elems (32KB)
  unsigned short* Bs = sm + 2 * 128 * 64;  // 2*128*64 elems (32KB)

  const int m0 = blockIdx.x * 128;
  const int n0 = blockIdx.y * 128;       // 0..2944
  const int z  = n0 >> 10;
  const int nloc = n0 & 1023;

  f32x4 acc[4][4];
  gemm_pipe<4, 4, 2>(Xb, Wf, m0, n0, DMODEL, As, Bs, acc);
  // gemm_pipe ends with __syncthreads -> safe to reuse sm

  const int tid  = threadIdx.x;
  const int lane = tid & 63;
  const int w    = tid >> 6;
  const int wr   = w >> 1, wc = w & 1;
  const int cb   = lane & 15, rb = (lane >> 4) * 4;

  if (z < 2) {
    #pragma unroll
    for (int mi = 0; mi < 4; ++mi)
      #pragma unroll
      for (int ni = 0; ni < 4; ++ni)
        #pragma unroll
        for (int r = 0; r < 4; ++r)
          sm[(wr * 64 + mi * 16 + rb + r) * TP + wc * 64 + ni * 16 + cb] = f2bf(acc[mi][ni][r]);
  } else {
    #pragma unroll
    for (int mi = 0; mi < 4; ++mi)
      #pragma unroll
      for (int ni = 0; ni < 4; ++ni)
        #pragma unroll
        for (int r = 0; r < 4; ++r)
          sm[(wc * 64 + ni * 16 + cb) * TP + wr * 64 + mi * 16 + rb + r] = f2bf(acc[mi][ni][r]);
  }
  __syncthreads();

  const int b = m0 >> 11;
  const float l2t = 13.28771237954945f / 32.0f;   // log2(10000)/32
  const float qsc = (z == 0) ? 0.18033688011112042f : 1.0f;  // 0.125*log2(e)

  if (z < 2) {
    unsigned short* dst = (z == 0) ? Qh : Kh;
    #pragma unroll
    for (int p = 0; p < 8; ++p) {
      const int m_l = p * 16 + (tid >> 4);
      const int ck  = tid & 15;
      bf16x8 vals = *(const bf16x8*)(sm + m_l * TP + ck * 8);
      const int m = m0 + m_l, s = m & (SS - 1);
      const int pos = tpos[m];
      const int n = nloc + ck * 8, h = n >> 6, dh = n & 63;
      union { unsigned short u[8]; uint4 v; } ov;
      #pragma unroll
      for (int e = 0; e < 4; ++e) {
        float x1 = (float)vals[2 * e], x2 = (float)vals[2 * e + 1];
        int j = (dh >> 1) + e;
        float ang = (float)pos * exp2f(-(float)j * l2t);
        float sn, cs;
        __sincosf(ang, &sn, &cs);
        sn *= qsc; cs *= qsc;
        ov.u[2 * e]     = f2bf(x1 * cs - x2 * sn);
        ov.u[2 * e + 1] = f2bf(x1 * sn + x2 * cs);
      }
      *(uint4*)(dst + ((size_t)(b * NH + h) * SS + s) * DKH + dh) = ov.v;
    }
  } else {
    #pragma unroll
    for (int p = 0; p < 8; ++p) {
      const int n_l = p * 16 + (tid >> 4);
      const int ck  = tid & 15;
      bf16x8 vals = *(const bf16x8*)(sm + n_l * TP + ck * 8);
      const int n = nloc + n_l, h = n >> 6, dh = n & 63;
      const int m = m0 + ck * 8, s = m & (SS - 1);
      *(bf16x8*)(Vt + ((size_t)(b * NH + h) * DKH + dh) * SS + s) = vals;
    }
  }
}

// ---- flash attention (causal), 128-q x 128-kv, equal-length pairing --------
// qt = ((j&7)<<1)|(j>>3): co-resident pair (idx, idx+256) gets qt = (2k,2k+1)
// -> both blocks on a CU run ~equal iteration counts, keeping 2-block
// residency for the WHOLE kernel (R18's complementary pairing left the long
// block alone at 1 wave/SIMD for ~15 iters = the entire 48us makespan).
// Bijection only: per-(bh,qt) math unchanged -> bit-identical output.
// bh = 4*(idx&7)+s keeps K/V L2-resident (R11). Fixed-base softmax (R13).
__global__ __launch_bounds__(256) void attn(
    const unsigned short* __restrict__ Qh,
    const unsigned short* __restrict__ Kh,
    const unsigned short* __restrict__ Vt,
    unsigned short* __restrict__ comb)  // [B,S,1024]
{
  __shared__ unsigned short Ks[2][128 * 64];  // [kv][d], chunk^row swizzled
  __shared__ unsigned short Vs[2][64 * 128];  // [d][kv], chunk^row swizzled
  __shared__ unsigned short Ps[4][32 * 64];   // per-wave P (32 q), swizzled

  const int idx = blockIdx.x;          // 0..511
  const int x = idx & 7;               // presumed XCD
  const int o = idx >> 3;              // 0..63
  const int bh = x * 4 + (o & 3);      // 4 heads per XCD
  const int j = o >> 2;                // 0..15
  const int qt = ((j & 7) << 1) | (j >> 3);  // pair(j, j+8) -> qt (2k, 2k+1)

  const int tid = threadIdx.x, lane = tid & 63, w = tid >> 6;
  const int lc = lane & 15, lh = lane >> 4;

  const unsigned short* kb = Kh + (size_t)bh * SS * DKH;
  const unsigned short* vb = Vt + (size_t)bh * DKH * SS;
  const int b = bh >> 4, h = bh & 15;
  const f32x4 fzero = {0.f, 0.f, 0.f, 0.f};
  const int Q0 = qt * 128;

  auto STAGE = [&](int t, int buf) {
    const int kv0 = t * 128;
    #pragma unroll
    for (int c = 0; c < 4; ++c) {        // K: 1024 x 16B chunks
      int i = tid + c * 256;
      int row = i >> 3, pc = i & 7;
      int sc = pc ^ (row & 7);
      GLL(kb + (size_t)(kv0 + row) * DKH + sc * 8, &Ks[buf][i * 8]);
    }
    #pragma unroll
    for (int c = 0; c < 4; ++c) {        // V: 1024 x 16B chunks, rows are d
      int i = tid + c * 256;
      int row = i >> 4, cc = i & 15;
      int sc = cc ^ (row & 7);
      GLL(vb + (size_t)row * SS + kv0 + sc * 8, &Vs[buf][i * 8]);
    }
  };

  // Q fragments for both q-groups (wave owns q = Q0 + w*32 + qg*16 + lc)
  bf16x8 qf[2][2];
  #pragma unroll
  for (int qg = 0; qg < 2; ++qg) {
    const unsigned short* Qb = Qh + ((size_t)bh * SS + Q0 + w * 32 + qg * 16 + lc) * DKH;
    qf[qg][0] = *(const bf16x8*)(Qb + lh * 8);
    qf[qg][1] = *(const bf16x8*)(Qb + lh * 8 + 32);
  }

  f32x4 oacc[2][4];
  #pragma unroll
  for (int qg = 0; qg < 2; ++qg)
    #pragma unroll
    for (int i = 0; i < 4; ++i) oacc[qg][i] = fzero;
  float lsum[2] = {0.f, 0.f};
  unsigned short* psw = &Ps[w][0];

  // QK^T over kv-half hh (64 kv); K fragments shared by both q-groups
  auto QK = [&](int cur, int hh, f32x4 (&sacc)[2][4]) {
    __builtin_amdgcn_s_setprio(1);
    #pragma unroll
    for (int nf = 0; nf < 4; ++nf) {
      const int row = hh * 64 + nf * 16 + lc;
      bf16x8 kf0 = *(const bf16x8*)(&Ks[cur][row * 64 + ((lh) ^ (row & 7)) * 8]);
      bf16x8 kf1 = *(const bf16x8*)(&Ks[cur][row * 64 + ((lh + 4) ^ (row & 7)) * 8]);
      #pragma unroll
      for (int qg = 0; qg < 2; ++qg) {
        sacc[qg][nf] = __builtin_amdgcn_mfma_f32_16x16x32_bf16(kf0, qf[qg][0], fzero, 0, 0, 0);
        sacc[qg][nf] = __builtin_amdgcn_mfma_f32_16x16x32_bf16(kf1, qf[qg][1], sacc[qg][nf], 0, 0, 0);
      }
    }
    __builtin_amdgcn_s_setprio(0);
  };

  auto SM = [&](f32x4 (&sacc)[2][4], bool domask, int t, int hh) {
    #pragma unroll
    for (int qg = 0; qg < 2; ++qg) {
      float sv[4][4];
      if (domask) {
        const int kv0 = t * 128 + hh * 64;
        const int qlane = Q0 + w * 32 + qg * 16 + lc;
        #pragma unroll
        for (int nf = 0; nf < 4; ++nf)
          #pragma unroll
          for (int r = 0; r < 4; ++r) {
            float x2 = sacc[qg][nf][r];
            if ((kv0 + nf * 16 + lh * 4 + r) > qlane) x2 = -1e30f;
            sv[nf][r] = x2;
          }
      } else {
        #pragma unroll
        for (int nf = 0; nf < 4; ++nf)
          #pragma unroll
          for (int r = 0; r < 4; ++r)
            sv[nf][r] = sacc[qg][nf][r];
      }
      float rs = 0.f;
      #pragma unroll
      for (int nf = 0; nf < 4; ++nf)
        #pragma unroll
        for (int r = 0; r < 4; ++r) {
          float p = exp2f(sv[nf][r]);
          sv[nf][r] = p;
          rs += p;
        }
      lsum[qg] += rs;
      #pragma unroll
      for (int nf = 0; nf < 4; ++nf) {
        uint32_t u0, u1;
        asm("v_cvt_pk_bf16_f32 %0, %1, %2" : "=v"(u0) : "v"(sv[nf][0]), "v"(sv[nf][1]));
        asm("v_cvt_pk_bf16_f32 %0, %1, %2" : "=v"(u1) : "v"(sv[nf][2]), "v"(sv[nf][3]));
        int swz = (nf * 2 + (lh >> 1)) ^ (lc & 7);
        uint32_t* p = (uint32_t*)&psw[(qg * 16 + lc) * 64 + swz * 8 + (lh & 1) * 4];
        p[0] = u0; p[1] = u1;
      }
    }
  };

  // PV over kv-half hh; V fragments shared by both q-groups
  auto PV = [&](int cur, int hh) {
    __builtin_amdgcn_s_setprio(1);
    #pragma unroll
    for (int c = 0; c < 2; ++c) {
      bf16x8 pf[2];
      #pragma unroll
      for (int qg = 0; qg < 2; ++qg)
        pf[qg] = *(const bf16x8*)(&psw[(qg * 16 + lc) * 64 + ((c * 4 + lh) ^ (lc & 7)) * 8]);
      #pragma unroll
      for (int df = 0; df < 4; ++df) {
        const int row = df * 16 + lc;
        bf16x8 vf = *(const bf16x8*)(&Vs[cur][row * 128 + ((hh * 8 + c * 4 + lh) ^ (row & 7)) * 8]);
        #pragma unroll
        for (int qg = 0; qg < 2; ++qg)
          oacc[qg][df] = __builtin_amdgcn_mfma_f32_16x16x32_bf16(pf[qg], vf, oacc[qg][df], 0, 0, 0);
      }
    }
    __builtin_amdgcn_s_setprio(0);
  };

  STAGE(0, 0);
  for (int t = 0; t < qt; ++t) {          // mask-free main loop
    const int cur = t & 1;
    asm volatile("s_waitcnt vmcnt(0)" ::: "memory");
    __builtin_amdgcn_s_barrier();
    f32x4 sA[2][4], sB[2][4];
    QK(cur, 0, sA);
    QK(cur, 1, sB);
    STAGE(t + 1, cur ^ 1);                // prefetch under remaining compute
    SM(sA, false, t, 0);
    PV(cur, 0);
    SM(sB, false, t, 1);
    PV(cur, 1);
  }
  {                                        // diagonal tile t == qt (both halves masked)
    const int cur = qt & 1;
    asm volatile("s_waitcnt vmcnt(0)" ::: "memory");
    __builtin_amdgcn_s_barrier();
    f32x4 sA[2][4], sB[2][4];
    QK(cur, 0, sA);
    QK(cur, 1, sB);
    SM(sA, true, qt, 0);
    PV(cur, 0);
    SM(sB, true, qt, 1);
    PV(cur, 1);
  }

  #pragma unroll
  for (int qg = 0; qg < 2; ++qg) {
    float ls0 = lsum[qg];
    ls0 += __shfl_xor(ls0, 16);
    ls0 += __shfl_xor(ls0, 32);
    #pragma unroll
    for (int r = 0; r < 4; ++r) {
      float ls = __shfl(ls0, lh * 4 + r);
      float inv = 1.f / ls;
      const int q = Q0 + w * 32 + qg * 16 + lh * 4 + r;
      #pragma unroll
      for (int df = 0; df < 4; ++df) {
        const int d = h * 64 + df * 16 + lc;
        comb[((size_t)(b * SS + q)) * DMODEL + d] = f2bf(oacc[qg][df][r] * inv);
      }
    }
  }
}

// ---- output projection: 128x64 tiles, KU=2, f32 epilogue -------------------
__global__ __launch_bounds__(256) void gemm_out(
    const unsigned short* __restrict__ Cb,
    const unsigned short* __restrict__ Wob,
    float* __restrict__ out)
{
  __shared__ __align__(16) unsigned char smraw[49152];  // staging 48KB / epi 34KB
  unsigned short* As = (unsigned short*)smraw;                 // 2*128*64 elems
  unsigned short* Bs = (unsigned short*)smraw + 2 * 128 * 64;  // 2*64*64 elems
  float* smf = (float*)smraw;                                  // [128][68] f32 view

  const int m0 = blockIdx.x * 128, n0 = blockIdx.y * 64;
  f32x4 acc[4][2];
  gemm_pipe<4, 2, 2>(Cb, Wob, m0, n0, DMODEL, As, Bs, acc);
  // gemm_pipe ends with __syncthreads -> safe to reuse LDS

  const int tid  = threadIdx.x;
  const int lane = tid & 63;
  const int w    = tid >> 6;
  const int wr   = w >> 1, wc = w & 1;
  const int cb   = lane & 15, rb = (lane >> 4) * 4;

  #pragma unroll
  for (int mi = 0; mi < 4; ++mi)
    #pragma unroll
    for (int ni = 0; ni < 2; ++ni)
      #pragma unroll
      for (int r = 0; r < 4; ++r)
        smf[(wr * 64 + mi * 16 + rb + r) * 68 + wc * 32 + ni * 16 + cb] = acc[mi][ni][r];
  __syncthreads();

  #pragma unroll
  for (int p = 0; p < 8; ++p) {
    const int row = p * 16 + (tid >> 4);
    const int ck  = tid & 15;
    float4 vv = *(const float4*)(smf + row * 68 + ck * 4);
    *(float4*)(out + (size_t)(m0 + row) * DMODEL + n0 + ck * 4) = vv;
  }
}

extern "C" void kernel_launch(void* const* d_in, const int* in_sizes, int n_in,
                              void* d_out, int out_size, void* d_ws, size_t ws_size,
                              hipStream_t stream) {
  (void)in_sizes; (void)n_in; (void)out_size; (void)ws_size;
  const float* X    = (const float*)d_in[0];
  const int*   tpos = (const int*)d_in[1];
  const float* Wq   = (const float*)d_in[2];
  const float* Wk   = (const float*)d_in[3];
  const float* Wv   = (const float*)d_in[4];
  const float* Wo   = (const float*)d_in[5];
  float* out = (float*)d_out;

  uint8_t* ws = (uint8_t*)d_ws;
  const size_t SZ_X = (size_t)MTOT * DMODEL * 2;      // 8 MB
  const size_t SZ_W = (size_t)DMODEL * DMODEL * 2;    // 2 MB
  const size_t SZ_H = (size_t)BB * NH * SS * DKH * 2; // 8 MB
  unsigned short* Xb   = (unsigned short*)(ws);
  unsigned short* Wqb  = (unsigned short*)(ws + SZ_X);         // [Wq;Wk;Wv;Wo]
  unsigned short* Wob  = (unsigned short*)(ws + SZ_X + 3 * SZ_W);
  unsigned short* Qh   = (unsigned short*)(ws + SZ_X + 4 * SZ_W);
  unsigned short* Kh   = (unsigned short*)(ws + SZ_X + 4 * SZ_W + SZ_H);
  unsigned short* Vt   = (unsigned short*)(ws + SZ_X + 4 * SZ_W + 2 * SZ_H);
  unsigned short* comb = Xb;  // Xb dead after QKV projection

  cvt_all<<<dim3(4096), dim3(256), 0, stream>>>(X, Wq, Wk, Wv, Wo, Xb, Wqb);

  gemm_qkv<<<dim3(MTOT / 128, 24), dim3(256), 0, stream>>>(Xb, Wqb, tpos, Qh, Kh, Vt);
  attn<<<dim3(512), dim3(256), 0, stream>>>(Qh, Kh, Vt, comb);
  gemm_out<<<dim3(MTOT / 128, 16), dim3(256), 0, stream>>>(comb, Wob, out);
}

// Round 20
// 96.955 us; speedup vs baseline: 1.2042x; 1.2042x over previous
//
#include <hip/hip_runtime.h>
#include <hip/hip_bf16.h>
#include <stdint.h>

#define DMODEL 1024
#define NH 16
#define DKH 64
#define BB 2
#define SS 2048
#define MTOT (BB*SS)   // 4096

#define TP 136   // padded LDS stride (elems) for 128-wide tiles

using f32x4  = __attribute__((ext_vector_type(4))) float;
using bf16x8 = __attribute__((ext_vector_type(8))) __bf16;

// async global->LDS, 16B per lane. LDS dest must be wave-uniform base + lane*16.
#define GLL(g, l) __builtin_amdgcn_global_load_lds( \
    (const __attribute__((address_space(1))) unsigned int*)(g), \
    (__attribute__((address_space(3))) unsigned int*)(l), 16, 0, 0)

__device__ __forceinline__ unsigned short f2bf(float f) {
  union { float f; uint32_t u; } v; v.f = f;
  uint32_t r = v.u + 0x7FFFu + ((v.u >> 16) & 1u);
  return (unsigned short)(r >> 16);
}

// one launch converts X and all 4 weight matrices to bf16
__global__ __launch_bounds__(256) void cvt_all(
    const float* __restrict__ X,
    const float* __restrict__ w0, const float* __restrict__ w1,
    const float* __restrict__ w2, const float* __restrict__ w3,
    unsigned short* __restrict__ Xb,
    unsigned short* __restrict__ Wb)   // [Wq;Wk;Wv;Wo] contiguous
{
  const int bid = blockIdx.x;
  const float* src;
  unsigned short* dst;
  int i;
  if (bid < 2048) {                      // X: 4M elems = 2048 blocks
    src = X; dst = Xb; i = bid * 256 + threadIdx.x;
  } else {                               // each W: 1M elems = 512 blocks
    int t = bid - 2048;
    int z = t >> 9;
    src = (z == 0) ? w0 : (z == 1) ? w1 : (z == 2) ? w2 : w3;
    dst = Wb + (size_t)z * DMODEL * DMODEL;
    i = (t & 511) * 256 + threadIdx.x;
  }
  const float4* s4 = (const float4*)src;
  float4 a = s4[2*i], b = s4[2*i+1];
  uint4 o;
  o.x = (uint32_t)f2bf(a.x) | ((uint32_t)f2bf(a.y) << 16);
  o.y = (uint32_t)f2bf(a.z) | ((uint32_t)f2bf(a.w) << 16);
  o.z = (uint32_t)f2bf(b.x) | ((uint32_t)f2bf(b.y) << 16);
  o.w = (uint32_t)f2bf(b.z) | ((uint32_t)f2bf(b.w) << 16);
  *(uint4*)(dst + (size_t)i * 8) = o;
}

// ---- pipelined double-buffered NT-GEMM mainloop ----------------------------
// KU = k-unroll: BKT = 32*KU elems staged per step. KU=2 halves the step
// count (and per-step barrier/drain fixed cost) at identical math order.
template<int MI, int NI, int KU>
__device__ __forceinline__ void gemm_pipe(
    const unsigned short* __restrict__ A,
    const unsigned short* __restrict__ Bw,
    int m0, int n0, int K,
    unsigned short* As, unsigned short* Bs,
    f32x4 (&acc)[MI][NI])
{
  const int BKT = 32 * KU;
  const int BMl = MI * 32;
  const int BNl = NI * 32;
  const int tid = threadIdx.x;
  const int lane = tid & 63;
  const int w = tid >> 6;
  const int wr = w >> 1, wc = w & 1;
  const int lrow = lane & 15;
  const int g = lane >> 4;

  const f32x4 fzero = {0.f, 0.f, 0.f, 0.f};
  #pragma unroll
  for (int i = 0; i < MI; ++i)
    #pragma unroll
    for (int j = 0; j < NI; ++j)
      acc[i][j] = fzero;

  const int nk = K / BKT;

  // hoisted per-thread staging sources and LDS chunk offsets
  const unsigned short* aSrc[(MI * KU) / 2];
  const unsigned short* bSrc[(NI * KU) / 2];
  int aLds[(MI * KU) / 2], bLds[(NI * KU) / 2];
  #pragma unroll
  for (int c = 0; c < (MI * KU) / 2; ++c) {
    int i = tid + c * 256;
    int row, sc;
    if constexpr (KU == 1) { row = i >> 2; sc = (i & 3) ^ ((row >> 1) & 3); }
    else                   { row = i >> 3; sc = (i & 7) ^ (row & 7); }
    aSrc[c] = A + (size_t)(m0 + row) * K + sc * 8;
    aLds[c] = i * 8;
  }
  #pragma unroll
  for (int c = 0; c < (NI * KU) / 2; ++c) {
    int i = tid + c * 256;
    int row, sc;
    if constexpr (KU == 1) { row = i >> 2; sc = (i & 3) ^ ((row >> 1) & 3); }
    else                   { row = i >> 3; sc = (i & 7) ^ (row & 7); }
    bSrc[c] = Bw + (size_t)(n0 + row) * K + sc * 8;
    bLds[c] = i * 8;
  }
  // hoisted fragment read offsets (per k-sub-step u)
  int aOff[KU][MI], bOff[KU][NI];
  #pragma unroll
  for (int u = 0; u < KU; ++u) {
    #pragma unroll
    for (int mi = 0; mi < MI; ++mi) {
      int row = wr * (MI * 16) + mi * 16 + lrow;
      int ch = (KU == 1) ? (g ^ ((row >> 1) & 3)) : ((g + 4 * u) ^ (row & 7));
      aOff[u][mi] = row * BKT + ch * 8;
    }
    #pragma unroll
    for (int ni = 0; ni < NI; ++ni) {
      int row = wc * (NI * 16) + ni * 16 + lrow;
      int ch = (KU == 1) ? (g ^ ((row >> 1) & 3)) : ((g + 4 * u) ^ (row & 7));
      bOff[u][ni] = row * BKT + ch * 8;
    }
  }

  auto STAGE = [&](int k0, int buf) {
    #pragma unroll
    for (int c = 0; c < (MI * KU) / 2; ++c)
      GLL(aSrc[c] + k0, As + buf * (BMl * BKT) + aLds[c]);
    #pragma unroll
    for (int c = 0; c < (NI * KU) / 2; ++c)
      GLL(bSrc[c] + k0, Bs + buf * (BNl * BKT) + bLds[c]);
  };

  STAGE(0, 0);
  __syncthreads();
  for (int t = 0; t < nk; ++t) {
    const int cur = t & 1;
    if (t + 1 < nk) STAGE((t + 1) * BKT, cur ^ 1);

    const unsigned short* Ab = As + cur * (BMl * BKT);
    const unsigned short* Bb = Bs + cur * (BNl * BKT);
    #pragma unroll
    for (int u = 0; u < KU; ++u) {
      bf16x8 af[MI], bfr[NI];
      #pragma unroll
      for (int mi = 0; mi < MI; ++mi)
        af[mi] = *(const bf16x8*)(Ab + aOff[u][mi]);
      #pragma unroll
      for (int ni = 0; ni < NI; ++ni)
        bfr[ni] = *(const bf16x8*)(Bb + bOff[u][ni]);
      #pragma unroll
      for (int mi = 0; mi < MI; ++mi)
        #pragma unroll
        for (int ni = 0; ni < NI; ++ni)
          acc[mi][ni] = __builtin_amdgcn_mfma_f32_16x16x32_bf16(af[mi], bfr[ni], acc[mi][ni], 0, 0, 0);
    }

    __syncthreads();
  }
}

// ---- fused QKV projection + RoPE + head-split store (R18 proven) -----------
__global__ __launch_bounds__(256) void gemm_qkv(
    const unsigned short* __restrict__ Xb,
    const unsigned short* __restrict__ Wf,   // [3072][1024]
    const int* __restrict__ tpos,
    unsigned short* __restrict__ Qh,    // [B,H,S,64]
    unsigned short* __restrict__ Kh,    // [B,H,S,64]
    unsigned short* __restrict__ Vt)    // [B,H,64,S]
{
  __shared__ __align__(16) unsigned char smraw[65536];  // 2buf x (A+B) x 128x64
  unsigned short* sm = (unsigned short*)smraw;
  unsigned short* As = sm;                 // 2*128*64 elems (32KB)
  unsigned short* Bs = sm + 2 * 128 * 64;  // 2*128*64 elems (32KB)

  const int m0 = blockIdx.x * 128;
  const int n0 = blockIdx.y * 128;       // 0..2944
  const int z  = n0 >> 10;
  const int nloc = n0 & 1023;

  f32x4 acc[4][4];
  gemm_pipe<4, 4, 2>(Xb, Wf, m0, n0, DMODEL, As, Bs, acc);
  // gemm_pipe ends with __syncthreads -> safe to reuse sm

  const int tid  = threadIdx.x;
  const int lane = tid & 63;
  const int w    = tid >> 6;
  const int wr   = w >> 1, wc = w & 1;
  const int cb   = lane & 15, rb = (lane >> 4) * 4;

  if (z < 2) {
    #pragma unroll
    for (int mi = 0; mi < 4; ++mi)
      #pragma unroll
      for (int ni = 0; ni < 4; ++ni)
        #pragma unroll
        for (int r = 0; r < 4; ++r)
          sm[(wr * 64 + mi * 16 + rb + r) * TP + wc * 64 + ni * 16 + cb] = f2bf(acc[mi][ni][r]);
  } else {
    #pragma unroll
    for (int mi = 0; mi < 4; ++mi)
      #pragma unroll
      for (int ni = 0; ni < 4; ++ni)
        #pragma unroll
        for (int r = 0; r < 4; ++r)
          sm[(wc * 64 + ni * 16 + cb) * TP + wr * 64 + mi * 16 + rb + r] = f2bf(acc[mi][ni][r]);
  }
  __syncthreads();

  const int b = m0 >> 11;
  const float l2t = 13.28771237954945f / 32.0f;   // log2(10000)/32
  const float qsc = (z == 0) ? 0.18033688011112042f : 1.0f;  // 0.125*log2(e)

  if (z < 2) {
    unsigned short* dst = (z == 0) ? Qh : Kh;
    #pragma unroll
    for (int p = 0; p < 8; ++p) {
      const int m_l = p * 16 + (tid >> 4);
      const int ck  = tid & 15;
      bf16x8 vals = *(const bf16x8*)(sm + m_l * TP + ck * 8);
      const int m = m0 + m_l, s = m & (SS - 1);
      const int pos = tpos[m];
      const int n = nloc + ck * 8, h = n >> 6, dh = n & 63;
      union { unsigned short u[8]; uint4 v; } ov;
      #pragma unroll
      for (int e = 0; e < 4; ++e) {
        float x1 = (float)vals[2 * e], x2 = (float)vals[2 * e + 1];
        int j = (dh >> 1) + e;
        float ang = (float)pos * exp2f(-(float)j * l2t);
        float sn, cs;
        __sincosf(ang, &sn, &cs);
        sn *= qsc; cs *= qsc;
        ov.u[2 * e]     = f2bf(x1 * cs - x2 * sn);
        ov.u[2 * e + 1] = f2bf(x1 * sn + x2 * cs);
      }
      *(uint4*)(dst + ((size_t)(b * NH + h) * SS + s) * DKH + dh) = ov.v;
    }
  } else {
    #pragma unroll
    for (int p = 0; p < 8; ++p) {
      const int n_l = p * 16 + (tid >> 4);
      const int ck  = tid & 15;
      bf16x8 vals = *(const bf16x8*)(sm + n_l * TP + ck * 8);
      const int n = nloc + n_l, h = n >> 6, dh = n & 63;
      const int m = m0 + ck * 8, s = m & (SS - 1);
      *(bf16x8*)(Vt + ((size_t)(b * NH + h) * DKH + dh) * SS + s) = vals;
    }
  }
}

// ---- flash attention (causal), 128-q x 128-kv, 8 waves (2/SIMD) ------------
// 512 threads: wave w owns 16 q-rows (wq = w>>1, qg = w&1). Two sibling waves
// per SIMD interleave independent chains between barriers -> intra-SIMD
// latency hiding that cross-block residency failed to provide (R19: two
// blocks/CU nearly serialize; R13-R18: 1 wave/SIMD chain fully exposed).
// Per-q operand values, kv order, and accumulation identical -> bit-identical.
// Pairing reverted to complementary (j<8?j:23-j, R17-proven).
// bh = 4*(idx&7)+s keeps K/V L2-resident (R11). Fixed-base softmax (R13).
__global__ __launch_bounds__(512) void attn(
    const unsigned short* __restrict__ Qh,
    const unsigned short* __restrict__ Kh,
    const unsigned short* __restrict__ Vt,
    unsigned short* __restrict__ comb)  // [B,S,1024]
{
  __shared__ unsigned short Ks[2][128 * 64];  // [kv][d], chunk^row swizzled
  __shared__ unsigned short Vs[2][64 * 128];  // [d][kv], chunk^row swizzled
  __shared__ unsigned short Ps[8][16 * 64];   // per-wave P (16 q), swizzled

  const int idx = blockIdx.x;          // 0..511
  const int x = idx & 7;               // presumed XCD
  const int o = idx >> 3;              // 0..63
  const int bh = x * 4 + (o & 3);      // 4 heads per XCD
  const int j = o >> 2;                // 0..15
  const int qt = (j < 8) ? j : 23 - j; // complementary pairing (R17)

  const int tid = threadIdx.x, lane = tid & 63, w = tid >> 6;  // w 0..7
  const int lc = lane & 15, lh = lane >> 4;
  const int wq = w >> 1, qg = w & 1;

  const unsigned short* kb = Kh + (size_t)bh * SS * DKH;
  const unsigned short* vb = Vt + (size_t)bh * DKH * SS;
  const int b = bh >> 4, h = bh & 15;
  const f32x4 fzero = {0.f, 0.f, 0.f, 0.f};
  const int Q0 = qt * 128;

  auto STAGE = [&](int t, int buf) {
    const int kv0 = t * 128;
    #pragma unroll
    for (int c = 0; c < 2; ++c) {        // K: 1024 x 16B chunks (512 thr x 2)
      int i = tid + c * 512;
      int row = i >> 3, pc = i & 7;
      int sc = pc ^ (row & 7);
      GLL(kb + (size_t)(kv0 + row) * DKH + sc * 8, &Ks[buf][i * 8]);
    }
    #pragma unroll
    for (int c = 0; c < 2; ++c) {        // V: 1024 x 16B chunks, rows are d
      int i = tid + c * 512;
      int row = i >> 4, cc = i & 15;
      int sc = cc ^ (row & 7);
      GLL(vb + (size_t)row * SS + kv0 + sc * 8, &Vs[buf][i * 8]);
    }
  };

  // Q fragment: this wave's 16 q-rows (q = Q0 + wq*32 + qg*16 + lc)
  const unsigned short* Qb = Qh + ((size_t)bh * SS + Q0 + wq * 32 + qg * 16 + lc) * DKH;
  bf16x8 qf0 = *(const bf16x8*)(Qb + lh * 8);
  bf16x8 qf1 = *(const bf16x8*)(Qb + lh * 8 + 32);

  f32x4 oacc[4];
  #pragma unroll
  for (int i = 0; i < 4; ++i) oacc[i] = fzero;
  float lsum = 0.f;
  unsigned short* psw = &Ps[w][0];

  // QK^T over kv-half hh (64 kv)
  auto QK = [&](int cur, int hh, f32x4 (&sacc)[4]) {
    __builtin_amdgcn_s_setprio(1);
    #pragma unroll
    for (int nf = 0; nf < 4; ++nf) {
      const int row = hh * 64 + nf * 16 + lc;
      bf16x8 kf0 = *(const bf16x8*)(&Ks[cur][row * 64 + ((lh) ^ (row & 7)) * 8]);
      bf16x8 kf1 = *(const bf16x8*)(&Ks[cur][row * 64 + ((lh + 4) ^ (row & 7)) * 8]);
      sacc[nf] = __builtin_amdgcn_mfma_f32_16x16x32_bf16(kf0, qf0, fzero, 0, 0, 0);
      sacc[nf] = __builtin_amdgcn_mfma_f32_16x16x32_bf16(kf1, qf1, sacc[nf], 0, 0, 0);
    }
    __builtin_amdgcn_s_setprio(0);
  };

  auto SM = [&](f32x4 (&sacc)[4], bool domask, int t, int hh) {
    float sv[4][4];
    if (domask) {
      const int kv0 = t * 128 + hh * 64;
      const int qlane = Q0 + wq * 32 + qg * 16 + lc;
      #pragma unroll
      for (int nf = 0; nf < 4; ++nf)
        #pragma unroll
        for (int r = 0; r < 4; ++r) {
          float x2 = sacc[nf][r];
          if ((kv0 + nf * 16 + lh * 4 + r) > qlane) x2 = -1e30f;
          sv[nf][r] = x2;
        }
    } else {
      #pragma unroll
      for (int nf = 0; nf < 4; ++nf)
        #pragma unroll
        for (int r = 0; r < 4; ++r)
          sv[nf][r] = sacc[nf][r];
    }
    float rs = 0.f;
    #pragma unroll
    for (int nf = 0; nf < 4; ++nf)
      #pragma unroll
      for (int r = 0; r < 4; ++r) {
        float p = exp2f(sv[nf][r]);
        sv[nf][r] = p;
        rs += p;
      }
    lsum += rs;   // per-lane partial; group-summed at epilogue
    #pragma unroll
    for (int nf = 0; nf < 4; ++nf) {
      uint32_t u0, u1;
      asm("v_cvt_pk_bf16_f32 %0, %1, %2" : "=v"(u0) : "v"(sv[nf][0]), "v"(sv[nf][1]));
      asm("v_cvt_pk_bf16_f32 %0, %1, %2" : "=v"(u1) : "v"(sv[nf][2]), "v"(sv[nf][3]));
      int swz = (nf * 2 + (lh >> 1)) ^ (lc & 7);
      uint32_t* p = (uint32_t*)&psw[lc * 64 + swz * 8 + (lh & 1) * 4];
      p[0] = u0; p[1] = u1;
    }
  };

  // PV over kv-half hh
  auto PV = [&](int cur, int hh) {
    __builtin_amdgcn_s_setprio(1);
    #pragma unroll
    for (int c = 0; c < 2; ++c) {
      bf16x8 pf = *(const bf16x8*)(&psw[lc * 64 + ((c * 4 + lh) ^ (lc & 7)) * 8]);
      #pragma unroll
      for (int df = 0; df < 4; ++df) {
        const int row = df * 16 + lc;
        bf16x8 vf = *(const bf16x8*)(&Vs[cur][row * 128 + ((hh * 8 + c * 4 + lh) ^ (row & 7)) * 8]);
        oacc[df] = __builtin_amdgcn_mfma_f32_16x16x32_bf16(pf, vf, oacc[df], 0, 0, 0);
      }
    }
    __builtin_amdgcn_s_setprio(0);
  };

  STAGE(0, 0);
  for (int t = 0; t < qt; ++t) {          // mask-free main loop
    const int cur = t & 1;
    asm volatile("s_waitcnt vmcnt(0)" ::: "memory");
    __builtin_amdgcn_s_barrier();
    f32x4 sA[4], sB[4];
    QK(cur, 0, sA);
    QK(cur, 1, sB);
    STAGE(t + 1, cur ^ 1);                // prefetch under remaining compute
    SM(sA, false, t, 0);
    PV(cur, 0);
    SM(sB, false, t, 1);
    PV(cur, 1);
  }
  {                                        // diagonal tile t == qt (both halves masked)
    const int cur = qt & 1;
    asm volatile("s_waitcnt vmcnt(0)" ::: "memory");
    __builtin_amdgcn_s_barrier();
    f32x4 sA[4], sB[4];
    QK(cur, 0, sA);
    QK(cur, 1, sB);
    SM(sA, true, qt, 0);
    PV(cur, 0);
    SM(sB, true, qt, 1);
    PV(cur, 1);
  }

  lsum += __shfl_xor(lsum, 16);
  lsum += __shfl_xor(lsum, 32);
  #pragma unroll
  for (int r = 0; r < 4; ++r) {
    float ls = __shfl(lsum, lh * 4 + r);
    float inv = 1.f / ls;
    const int q = Q0 + wq * 32 + qg * 16 + lh * 4 + r;
    #pragma unroll
    for (int df = 0; df < 4; ++df) {
      const int d = h * 64 + df * 16 + lc;
      comb[((size_t)(b * SS + q)) * DMODEL + d] = f2bf(oacc[df][r] * inv);
    }
  }
}

// ---- output projection: 128x64 tiles, KU=2, f32 epilogue -------------------
__global__ __launch_bounds__(256) void gemm_out(
    const unsigned short* __restrict__ Cb,
    const unsigned short* __restrict__ Wob,
    float* __restrict__ out)
{
  __shared__ __align__(16) unsigned char smraw[49152];  // staging 48KB / epi 34KB
  unsigned short* As = (unsigned short*)smraw;                 // 2*128*64 elems
  unsigned short* Bs = (unsigned short*)smraw + 2 * 128 * 64;  // 2*64*64 elems
  float* smf = (float*)smraw;                                  // [128][68] f32 view

  const int m0 = blockIdx.x * 128, n0 = blockIdx.y * 64;
  f32x4 acc[4][2];
  gemm_pipe<4, 2, 2>(Cb, Wob, m0, n0, DMODEL, As, Bs, acc);
  // gemm_pipe ends with __syncthreads -> safe to reuse LDS

  const int tid  = threadIdx.x;
  const int lane = tid & 63;
  const int w    = tid >> 6;
  const int wr   = w >> 1, wc = w & 1;
  const int cb   = lane & 15, rb = (lane >> 4) * 4;

  #pragma unroll
  for (int mi = 0; mi < 4; ++mi)
    #pragma unroll
    for (int ni = 0; ni < 2; ++ni)
      #pragma unroll
      for (int r = 0; r < 4; ++r)
        smf[(wr * 64 + mi * 16 + rb + r) * 68 + wc * 32 + ni * 16 + cb] = acc[mi][ni][r];
  __syncthreads();

  #pragma unroll
  for (int p = 0; p < 8; ++p) {
    const int row = p * 16 + (tid >> 4);
    const int ck  = tid & 15;
    float4 vv = *(const float4*)(smf + row * 68 + ck * 4);
    *(float4*)(out + (size_t)(m0 + row) * DMODEL + n0 + ck * 4) = vv;
  }
}

extern "C" void kernel_launch(void* const* d_in, const int* in_sizes, int n_in,
                              void* d_out, int out_size, void* d_ws, size_t ws_size,
                              hipStream_t stream) {
  (void)in_sizes; (void)n_in; (void)out_size; (void)ws_size;
  const float* X    = (const float*)d_in[0];
  const int*   tpos = (const int*)d_in[1];
  const float* Wq   = (const float*)d_in[2];
  const float* Wk   = (const float*)d_in[3];
  const float* Wv   = (const float*)d_in[4];
  const float* Wo   = (const float*)d_in[5];
  float* out = (float*)d_out;

  uint8_t* ws = (uint8_t*)d_ws;
  const size_t SZ_X = (size_t)MTOT * DMODEL * 2;      // 8 MB
  const size_t SZ_W = (size_t)DMODEL * DMODEL * 2;    // 2 MB
  const size_t SZ_H = (size_t)BB * NH * SS * DKH * 2; // 8 MB
  unsigned short* Xb   = (unsigned short*)(ws);
  unsigned short* Wqb  = (unsigned short*)(ws + SZ_X);         // [Wq;Wk;Wv;Wo]
  unsigned short* Wob  = (unsigned short*)(ws + SZ_X + 3 * SZ_W);
  unsigned short* Qh   = (unsigned short*)(ws + SZ_X + 4 * SZ_W);
  unsigned short* Kh   = (unsigned short*)(ws + SZ_X + 4 * SZ_W + SZ_H);
  unsigned short* Vt   = (unsigned short*)(ws + SZ_X + 4 * SZ_W + 2 * SZ_H);
  unsigned short* comb = Xb;  // Xb dead after QKV projection

  cvt_all<<<dim3(4096), dim3(256), 0, stream>>>(X, Wq, Wk, Wv, Wo, Xb, Wqb);

  gemm_qkv<<<dim3(MTOT / 128, 24), dim3(256), 0, stream>>>(Xb, Wqb, tpos, Qh, Kh, Vt);
  attn<<<dim3(512), dim3(512), 0, stream>>>(Qh, Kh, Vt, comb);
  gemm_out<<<dim3(MTOT / 128, 16), dim3(256), 0, stream>>>(comb, Wob, out);
}